// Round 14
// baseline (49.312 us; speedup 1.0000x reference)
//
#include <hip/hip_runtime.h>
#include <hip/hip_bf16.h>

#define DEVI __device__ __forceinline__

typedef __attribute__((ext_vector_type(8))) short s16x8;
typedef __attribute__((ext_vector_type(4))) short s16x4;
typedef __attribute__((ext_vector_type(4))) float f32x4;

// ---- problem constants ----
// x: (8, 384, 32, 32); heads=8, dk=32, dv=64; N=1024 tokens; Cqk=256, Cv=512
#define LOG2E 1.4426950408889634f

DEVI short f2bs(float f) {  // fp32 -> bf16 bits (RNE)
    unsigned u = __builtin_bit_cast(unsigned, f);
    unsigned r = (u + 0x7fffu + ((u >> 16) & 1u)) >> 16;
    return (short)r;
}

DEVI f32x4 mfma16(s16x8 a, s16x8 b, f32x4 c) {
    return __builtin_amdgcn_mfma_f32_16x16x32_bf16(a, b, c, 0, 0, 0);
}

// async global->LDS 16B copy; LDS dest linear in lane order, swizzle in gsrc
DEVI void gl_lds16(const short* g, short* l) {
    __builtin_amdgcn_global_load_lds(
        (const __attribute__((address_space(1))) unsigned*)(const void*)g,
        (__attribute__((address_space(3))) unsigned*)(void*)l, 16, 0, 0);
}

// ---------------- merged prep: x transpose+cvt AND weights cvt + BN fold ----------------
__global__ __launch_bounds__(256) void k_prep(
    const float* __restrict__ x, short* __restrict__ xt,
    const float* __restrict__ wq, const float* __restrict__ wk,
    const float* __restrict__ wv, const float* __restrict__ wp,
    short* __restrict__ wqkv, short* __restrict__ wpb,
    const float* gq, const float* bq, const float* mq, const float* vq,
    const float* gk, const float* bk, const float* mk, const float* vk,
    const float* gv, const float* bv, const float* mv, const float* vv,
    const float* gp, const float* bp, const float* mp, const float* vp,
    float* s_qkv, float* t_qkv, float* s_p, float* t_p) {
    __shared__ float tile[32][33];
    const int bid = blockIdx.x;
    const int t = threadIdx.x;
    if (bid < 3072) {
        const int ct = bid % 12, nt = (bid / 12) % 32, b = bid / 384;
        {
            const int j = t & 31, i0 = (t >> 5) * 4;
            const float* src = x + ((size_t)b * 384 + (size_t)ct * 32) * 1024 + nt * 32;
#pragma unroll
            for (int ii = 0; ii < 4; ++ii)
                tile[i0 + ii][j] = src[(size_t)(i0 + ii) * 1024 + j];
        }
        __syncthreads();
        {
            const int ii = t & 31, j0 = (t >> 5) * 4;
            short* dst = xt + ((size_t)b * 1024 + (size_t)nt * 32) * 384 + ct * 32;
#pragma unroll
            for (int jj = 0; jj < 4; ++jj)
                dst[(size_t)(j0 + jj) * 384 + ii] = f2bs(tile[ii][j0 + jj]);
        }
        return;
    }
    int i = (bid - 3072) * 256 + t;
    if (i < 1024) {
        const float *g, *bb, *mm, *vv_;
        int o = i;
        float post = 1.0f;
        if (i < 256)      { g = gq; bb = bq; mm = mq; vv_ = vq; post = LOG2E; }
        else if (i < 512) { g = gk; bb = bk; mm = mk; vv_ = vk; o = i - 256; }
        else              { g = gv; bb = bv; mm = mv; vv_ = vv; o = i - 512; }
        float s = g[o] * rsqrtf(vv_[o] + 1e-5f);
        s_qkv[i] = s * post;
        t_qkv[i] = (bb[o] - mm[o] * s) * post;
        if (i < 384) {
            float sp = gp[i] * rsqrtf(vp[i] + 1e-5f);
            s_p[i] = sp;
            t_p[i] = bp[i] - mp[i] * sp;
        }
    }
    const int NQKV = 1024 * 384;
    if (i < NQKV) {
        int o = i / 384;
        float v;
        if (o < 256)      v = wq[i];
        else if (o < 512) v = wk[i - 256 * 384];
        else              v = wv[i - 512 * 384];
        wqkv[i] = f2bs(v);
    } else {
        int j = i - NQKV;
        if (j < 384 * 512) wpb[j] = f2bs(wp[j]);
    }
}

// ---------------- QKV GEMM: LDS-staged 128x128 tile, BK=64 (2 sub-phases/barrier) ----------------
__global__ __launch_bounds__(256, 2) void k_gemm_qkv(
    const short* __restrict__ wqkv, const short* __restrict__ xt,
    const float* __restrict__ s_qkv, const float* __restrict__ t_qkv,
    short* __restrict__ Qw, short* __restrict__ Kw, short* __restrict__ Vw) {
    __shared__ short AB[2][16384];  // A [128][64] + B [128][64] shorts per buffer
    const int t = threadIdx.x, lane = t & 63, w = t >> 6;
    const int g = lane >> 4, l15 = lane & 15;
    const int wr = w >> 1, wc = w & 1;
    const int jb = blockIdx.x, mb = blockIdx.y;

    const int ar = t >> 3, au = t & 7;
    const int aperm = 8 * (au ^ (ar & 7));
    const short* gA = wqkv + (size_t)(mb * 128 + ar) * 384 + aperm;
    const short* gB = xt + (size_t)((size_t)jb * 128 + ar) * 384 + aperm;

    f32x4 acc[4][4];
#pragma unroll
    for (int mi = 0; mi < 4; ++mi)
#pragma unroll
        for (int ni = 0; ni < 4; ++ni) acc[mi][ni] = f32x4{0.f, 0.f, 0.f, 0.f};

    auto stage = [&](int kt, int buf) {
        short* base = AB[buf];
#pragma unroll
        for (int jj = 0; jj < 4; ++jj) {
            gl_lds16(gA + (size_t)(32 * jj) * 384 + kt * 64, base + t * 8 + jj * 2048);
            gl_lds16(gB + (size_t)(32 * jj) * 384 + kt * 64, base + 8192 + t * 8 + jj * 2048);
        }
    };

    stage(0, 0);
    __syncthreads();

    for (int kt = 0; kt < 6; ++kt) {
        if (kt < 5) stage(kt + 1, (kt + 1) & 1);
        const short* base = AB[kt & 1];
#pragma unroll
        for (int ksub = 0; ksub < 2; ++ksub) {
            const int kc = 8 * ((4 * ksub + g) ^ (l15 & 7));
            s16x8 a[4], b[4];
#pragma unroll
            for (int mi = 0; mi < 4; ++mi)
                a[mi] = *(const s16x8*)(base + (64 * wr + 16 * mi + l15) * 64 + kc);
#pragma unroll
            for (int ni = 0; ni < 4; ++ni)
                b[ni] = *(const s16x8*)(base + 8192 + (64 * wc + 16 * ni + l15) * 64 + kc);
#pragma unroll
            for (int mi = 0; mi < 4; ++mi)
#pragma unroll
                for (int ni = 0; ni < 4; ++ni)
                    acc[mi][ni] = mfma16(a[mi], b[ni], acc[mi][ni]);
        }
        __syncthreads();
    }

    const int m_base = mb * 128 + 64 * wr;
    const int j_base = jb * 128 + 64 * wc;
#pragma unroll
    for (int mi = 0; mi < 4; ++mi) {
        const int o0 = m_base + 16 * mi;
#pragma unroll
        for (int ni = 0; ni < 4; ++ni) {
            const int j = j_base + 16 * ni + l15;
            const int bb = j >> 10, n = j & 1023;
            if (o0 < 512) {
                const int o = o0 + 4 * g;
                const int isK = o0 >= 256;
                const int o2 = o - (isK ? 256 : 0);
                const int h = o2 >> 5, d0 = o2 & 31;
                s16x4 ov;
#pragma unroll
                for (int r = 0; r < 4; ++r)
                    ov[r] = f2bs(acc[mi][ni][r] * s_qkv[o + r] + t_qkv[o + r]);
                short* dst = (isK ? Kw : Qw) + (((size_t)bb * 8 + h) * 1024 + n) * 32 + d0;
                *(s16x4*)dst = ov;
            } else {
#pragma unroll
                for (int r = 0; r < 4; ++r) {
                    const int o = o0 + 4 * g + r;
                    float val = acc[mi][ni][r] * s_qkv[o] + t_qkv[o];
                    const int o2 = o - 512;
                    const int h = o2 >> 6, e = o2 & 63;
                    Vw[(((size_t)bb * 8 + h) * 64 + e) * 1024 + n] = f2bs(val);
                }
            }
        }
    }
}

// ---------------- attention: 3-buffer counted-vmcnt pipeline (stage 2 tiles ahead) ----------------
// Per-iter: issue stage(mt+2) [6 loads] -> compute tile mt -> wait -> s_barrier.
// Wait count = loads newer than tile mt+1: vmcnt(6) while staging continues,
// vmcnt(0) at the drain iteration (mt==6) -- the R13 tail-race fix.
__global__ __launch_bounds__(256, 2) void k_attn(const short* __restrict__ Qw,
                                                 const short* __restrict__ Kw,
                                                 const short* __restrict__ Vw,
                                                 short* __restrict__ Ow) {
    __shared__ short KV[3][12288];  // K 4096 + V 8192 shorts per buffer (72 KB total)
    const int t = threadIdx.x, lane = t & 63, w = t >> 6;
    const int g = lane >> 4, l15 = lane & 15;
    const int low3 = blockIdx.x & 7;
    const int mid = blockIdx.x >> 3;
    const int rb = mid & 7;
    const int bh = ((mid >> 3) << 3) | low3;
    const int n_base = rb * 128 + w * 32;
    const short* Qb = Qw + (size_t)bh * (1024 * 32);
    const short* Kb = Kw + (size_t)bh * (1024 * 32);
    const short* Vb = Vw + (size_t)bh * (64 * 1024);

    s16x8 qf[2];
#pragma unroll
    for (int i = 0; i < 2; ++i)
        qf[i] = *(const s16x8*)(Qb + (size_t)(n_base + 16 * i + l15) * 32 + 8 * g);

    const s16x8 onesf = {0x3F80, 0x3F80, 0x3F80, 0x3F80, 0x3F80, 0x3F80, 0x3F80, 0x3F80};

    const int skr = t >> 2, sku = t & 3;
    const short* gK = Kb + (size_t)skr * 32 + 8 * (sku ^ (skr & 3));
    const int vr = t >> 4, vu = t & 15;
    const short* gV = Vb + (size_t)vr * 1024 + 8 * (vu ^ (vr & 7));

    f32x4 oacc[2][4], lacc[2];
#pragma unroll
    for (int niq = 0; niq < 2; ++niq) {
        lacc[niq] = f32x4{0.f, 0.f, 0.f, 0.f};
#pragma unroll
        for (int ei = 0; ei < 4; ++ei) oacc[niq][ei] = f32x4{0.f, 0.f, 0.f, 0.f};
    }

    const int krow = 8 * (l15 >> 2) + (l15 & 3);
    const int kcol = 8 * (g ^ (l15 & 3));

    auto stage = [&](int m0, int buf) {
        short* base = KV[buf];
        gl_lds16(gK + m0 * 32, base + t * 8);
        gl_lds16(gK + (m0 + 64) * 32, base + (t + 256) * 8);
#pragma unroll
        for (int jj = 0; jj < 4; ++jj)
            gl_lds16(gV + (size_t)(16 * jj) * 1024 + m0, base + 4096 + t * 8 + jj * 2048);
    };

    // prologue: tiles 0 and 1 in flight; wait until tile 0 resident (6 newest may fly)
    stage(0, 0);
    stage(128, 1);
    asm volatile("s_waitcnt vmcnt(6)" ::: "memory");
    __builtin_amdgcn_s_barrier();

    for (int mt = 0; mt < 8; ++mt) {
        if (mt < 6) stage((mt + 2) * 128, (mt + 2) % 3);
        const short* base = KV[mt % 3];
#pragma unroll
        for (int msub = 0; msub < 2; ++msub) {
            const int mofs = 64 * msub;
            s16x8 kf[4];
            kf[0] = *(const s16x8*)(base + (krow + mofs + 0) * 32 + kcol);
            kf[1] = *(const s16x8*)(base + (krow + mofs + 4) * 32 + kcol);
            kf[2] = *(const s16x8*)(base + (krow + mofs + 32) * 32 + kcol);
            kf[3] = *(const s16x8*)(base + (krow + mofs + 36) * 32 + kcol);
            s16x8 vb[2][4];
#pragma unroll
            for (int ki = 0; ki < 2; ++ki)
#pragma unroll
                for (int ei = 0; ei < 4; ++ei) {
                    const int row = 16 * ei + l15;
                    vb[ki][ei] = *(const s16x8*)(base + 4096 + row * 128 +
                                                 8 * ((8 * msub + 4 * ki + g) ^ (row & 7)));
                }
            // S^T
            __builtin_amdgcn_s_setprio(1);
            f32x4 st[4][2];
#pragma unroll
            for (int mik = 0; mik < 4; ++mik)
#pragma unroll
                for (int niq = 0; niq < 2; ++niq)
                    st[mik][niq] = mfma16(kf[mik], qf[niq], f32x4{0.f, 0.f, 0.f, 0.f});
            __builtin_amdgcn_s_setprio(0);
            // P = exp2(S'); pack via __float2bfloat16 (pairs -> v_cvt_pk_bf16_f32)
            s16x4 pk[4][2];
#pragma unroll
            for (int mik = 0; mik < 4; ++mik)
#pragma unroll
                for (int niq = 0; niq < 2; ++niq) {
#pragma unroll
                    for (int r = 0; r < 4; ++r) {
                        float p = __builtin_amdgcn_exp2f(st[mik][niq][r]);
                        pk[mik][niq][r] =
                            __builtin_bit_cast(short, __float2bfloat16(p));
                    }
                }
            // PV + l
            __builtin_amdgcn_s_setprio(1);
#pragma unroll
            for (int ki = 0; ki < 2; ++ki)
#pragma unroll
                for (int niq = 0; niq < 2; ++niq) {
                    s16x8 pb = __builtin_shufflevector(pk[2 * ki][niq], pk[2 * ki + 1][niq],
                                                       0, 1, 2, 3, 4, 5, 6, 7);
                    lacc[niq] = mfma16(onesf, pb, lacc[niq]);
#pragma unroll
                    for (int ei = 0; ei < 4; ++ei)
                        oacc[niq][ei] = mfma16(vb[ki][ei], pb, oacc[niq][ei]);
                }
            __builtin_amdgcn_s_setprio(0);
        }
        if (mt < 7) {
            if (mt < 6) {
                asm volatile("s_waitcnt vmcnt(6)" ::: "memory");
            } else {
                asm volatile("s_waitcnt vmcnt(0)" ::: "memory");  // drain: tile 7 is newest
            }
            __builtin_amdgcn_s_barrier();
        }
    }

    // l is complete in every lane (row-broadcast by ones-MFMA)
    float li[2];
#pragma unroll
    for (int niq = 0; niq < 2; ++niq) li[niq] = __builtin_amdgcn_rcpf(lacc[niq][0]);

    const int b = bh >> 3, h = bh & 7;
#pragma unroll
    for (int niq = 0; niq < 2; ++niq) {
        const int n = n_base + 16 * niq + l15;
#pragma unroll
        for (int ei = 0; ei < 4; ++ei) {
            s16x4 ov;
#pragma unroll
            for (int r = 0; r < 4; ++r)
                ov[r] = f2bs(fmaxf(oacc[niq][ei][r] * li[niq], 0.f));
            *(s16x4*)(Ow + ((size_t)b * 1024 + n) * 512 + h * 64 + 16 * ei + 4 * g) = ov;
        }
    }
}

// ---------------- proj GEMM: 3-buffer counted-vmcnt pipeline, 64x64 tile, BK=64 ----------------
__global__ __launch_bounds__(256, 3) void k_proj(const short* __restrict__ wpb,
                                                 const short* __restrict__ Ow,
                                                 const float* __restrict__ s_p,
                                                 const float* __restrict__ t_p,
                                                 float* __restrict__ out) {
    __shared__ short AB[3][8192];  // 48 KB total
    const int t = threadIdx.x, lane = t & 63, w = t >> 6;
    const int g = lane >> 4, l15 = lane & 15;
    const int wr = w >> 1, wc = w & 1;
    const int jb = blockIdx.x, mb = blockIdx.y;

    const int ar = t >> 3, au = t & 7;
    const int aperm = 8 * (au ^ (ar & 7));
    const short* gA = wpb + (size_t)(mb * 64 + ar) * 512 + aperm;
    const short* gB = Ow + (size_t)((size_t)jb * 64 + ar) * 512 + aperm;

    f32x4 acc[2][2];
#pragma unroll
    for (int mi = 0; mi < 2; ++mi)
#pragma unroll
        for (int ni = 0; ni < 2; ++ni) acc[mi][ni] = f32x4{0.f, 0.f, 0.f, 0.f};

    auto stage = [&](int kt, int buf) {
        short* base = AB[buf];
#pragma unroll
        for (int jj = 0; jj < 2; ++jj) {
            gl_lds16(gA + (size_t)(32 * jj) * 512 + kt * 64, base + t * 8 + jj * 2048);
            gl_lds16(gB + (size_t)(32 * jj) * 512 + kt * 64, base + 4096 + t * 8 + jj * 2048);
        }
    };

    stage(0, 0);
    stage(1, 1);
    asm volatile("s_waitcnt vmcnt(4)" ::: "memory");
    __builtin_amdgcn_s_barrier();

    for (int kt = 0; kt < 8; ++kt) {
        if (kt < 6) stage(kt + 2, (kt + 2) % 3);
        const short* base = AB[kt % 3];
#pragma unroll
        for (int ksub = 0; ksub < 2; ++ksub) {
            const int kc = 8 * ((4 * ksub + g) ^ (l15 & 7));
            s16x8 a[2], b[2];
#pragma unroll
            for (int mi = 0; mi < 2; ++mi)
                a[mi] = *(const s16x8*)(base + (32 * wr + 16 * mi + l15) * 64 + kc);
#pragma unroll
            for (int ni = 0; ni < 2; ++ni)
                b[ni] = *(const s16x8*)(base + 4096 + (32 * wc + 16 * ni + l15) * 64 + kc);
#pragma unroll
            for (int mi = 0; mi < 2; ++mi)
#pragma unroll
                for (int ni = 0; ni < 2; ++ni)
                    acc[mi][ni] = mfma16(a[mi], b[ni], acc[mi][ni]);
        }
        if (kt < 7) {
            if (kt < 6) {
                asm volatile("s_waitcnt vmcnt(4)" ::: "memory");
            } else {
                asm volatile("s_waitcnt vmcnt(0)" ::: "memory");  // drain: tile 7 is newest
            }
            __builtin_amdgcn_s_barrier();
        }
    }

    const int m_base = mb * 64 + 32 * wr;
    const int j_base = jb * 64 + 32 * wc;
#pragma unroll
    for (int mi = 0; mi < 2; ++mi) {
#pragma unroll
        for (int ni = 0; ni < 2; ++ni) {
            const int j = j_base + 16 * ni + l15;
            const int bb = j >> 10, n = j & 1023;
#pragma unroll
            for (int r = 0; r < 4; ++r) {
                const int c = m_base + 16 * mi + 4 * g + r;
                float v = acc[mi][ni][r] * s_p[c] + t_p[c];
                out[((size_t)bb * 384 + c) * 1024 + n] = v;
            }
        }
    }
}

extern "C" void kernel_launch(void* const* d_in, const int* in_sizes, int n_in,
                              void* d_out, int out_size, void* d_ws, size_t ws_size,
                              hipStream_t stream) {
    const float* x  = (const float*)d_in[0];
    const float* wq = (const float*)d_in[1];
    const float* gq = (const float*)d_in[2];
    const float* bq = (const float*)d_in[3];
    const float* mq = (const float*)d_in[4];
    const float* vq = (const float*)d_in[5];
    const float* wk = (const float*)d_in[6];
    const float* gk = (const float*)d_in[7];
    const float* bk = (const float*)d_in[8];
    const float* mk = (const float*)d_in[9];
    const float* vk = (const float*)d_in[10];
    const float* wv = (const float*)d_in[11];
    const float* gv = (const float*)d_in[12];
    const float* bv = (const float*)d_in[13];
    const float* mv = (const float*)d_in[14];
    const float* vv = (const float*)d_in[15];
    const float* wp = (const float*)d_in[16];
    const float* gp = (const float*)d_in[17];
    const float* bp = (const float*)d_in[18];
    const float* mp = (const float*)d_in[19];
    const float* vp = (const float*)d_in[20];
    float* out = (float*)d_out;

    char* ws = (char*)d_ws;
    size_t off = 0;
    auto alloc = [&](size_t bytes) {
        char* p = ws + off;
        off += (bytes + 255) & ~(size_t)255;
        return p;
    };
    short* xt    = (short*)alloc((size_t)8 * 1024 * 384 * 2);
    short* wqkv  = (short*)alloc((size_t)1024 * 384 * 2);
    short* wpb   = (short*)alloc((size_t)384 * 512 * 2);
    float* s_qkv = (float*)alloc(1024 * 4);
    float* t_qkv = (float*)alloc(1024 * 4);
    float* s_p   = (float*)alloc(384 * 4);
    float* t_p   = (float*)alloc(384 * 4);
    short* Qw    = (short*)alloc((size_t)8 * 8 * 1024 * 32 * 2);
    short* Kw    = (short*)alloc((size_t)8 * 8 * 1024 * 32 * 2);
    short* Vw    = (short*)alloc((size_t)8 * 8 * 64 * 1024 * 2);
    short* Ow    = (short*)alloc((size_t)8 * 1024 * 512 * 2);
    (void)ws_size; (void)in_sizes; (void)n_in; (void)out_size;

    k_prep<<<dim3(3072 + 2304), 256, 0, stream>>>(
        x, xt, wq, wk, wv, wp, wqkv, wpb,
        gq, bq, mq, vq, gk, bk, mk, vk, gv, bv, mv, vv, gp, bp, mp, vp,
        s_qkv, t_qkv, s_p, t_p);
    k_gemm_qkv<<<dim3(64, 8), 256, 0, stream>>>(wqkv, xt, s_qkv, t_qkv, Qw, Kw, Vw);
    k_attn<<<dim3(512), 256, 0, stream>>>(Qw, Kw, Vw, Ow);
    k_proj<<<dim3(128, 6), 256, 0, stream>>>(wpb, Ow, s_p, t_p, out);
}

// Round 15
// 49.127 us; speedup vs baseline: 1.0038x; 1.0038x over previous
//
#include <hip/hip_runtime.h>
#include <hip/hip_bf16.h>

#define DEVI __device__ __forceinline__

typedef __attribute__((ext_vector_type(8))) short s16x8;
typedef __attribute__((ext_vector_type(4))) short s16x4;
typedef __attribute__((ext_vector_type(4))) float f32x4;

// ---- problem constants ----
// x: (8, 384, 32, 32); heads=8, dk=32, dv=64; N=1024 tokens; Cqk=256, Cv=512
#define LOG2E 1.4426950408889634f

DEVI short f2bs(float f) {  // fp32 -> bf16 bits (RNE)
    unsigned u = __builtin_bit_cast(unsigned, f);
    unsigned r = (u + 0x7fffu + ((u >> 16) & 1u)) >> 16;
    return (short)r;
}

DEVI f32x4 mfma16(s16x8 a, s16x8 b, f32x4 c) {
    return __builtin_amdgcn_mfma_f32_16x16x32_bf16(a, b, c, 0, 0, 0);
}

// async global->LDS 16B copy; LDS dest linear in lane order, swizzle in gsrc
DEVI void gl_lds16(const short* g, short* l) {
    __builtin_amdgcn_global_load_lds(
        (const __attribute__((address_space(1))) unsigned*)(const void*)g,
        (__attribute__((address_space(3))) unsigned*)(void*)l, 16, 0, 0);
}

// ---------------- merged prep: x transpose+cvt AND weights cvt + BN fold ----------------
__global__ __launch_bounds__(256) void k_prep(
    const float* __restrict__ x, short* __restrict__ xt,
    const float* __restrict__ wq, const float* __restrict__ wk,
    const float* __restrict__ wv, const float* __restrict__ wp,
    short* __restrict__ wqkv, short* __restrict__ wpb,
    const float* gq, const float* bq, const float* mq, const float* vq,
    const float* gk, const float* bk, const float* mk, const float* vk,
    const float* gv, const float* bv, const float* mv, const float* vv,
    const float* gp, const float* bp, const float* mp, const float* vp,
    float* s_qkv, float* t_qkv, float* s_p, float* t_p) {
    __shared__ float tile[32][33];
    const int bid = blockIdx.x;
    const int t = threadIdx.x;
    if (bid < 3072) {
        const int ct = bid % 12, nt = (bid / 12) % 32, b = bid / 384;
        {
            const int j = t & 31, i0 = (t >> 5) * 4;
            const float* src = x + ((size_t)b * 384 + (size_t)ct * 32) * 1024 + nt * 32;
#pragma unroll
            for (int ii = 0; ii < 4; ++ii)
                tile[i0 + ii][j] = src[(size_t)(i0 + ii) * 1024 + j];
        }
        __syncthreads();
        {
            const int ii = t & 31, j0 = (t >> 5) * 4;
            short* dst = xt + ((size_t)b * 1024 + (size_t)nt * 32) * 384 + ct * 32;
#pragma unroll
            for (int jj = 0; jj < 4; ++jj)
                dst[(size_t)(j0 + jj) * 384 + ii] = f2bs(tile[ii][j0 + jj]);
        }
        return;
    }
    int i = (bid - 3072) * 256 + t;
    if (i < 1024) {
        const float *g, *bb, *mm, *vv_;
        int o = i;
        float post = 1.0f;
        if (i < 256)      { g = gq; bb = bq; mm = mq; vv_ = vq; post = LOG2E; }
        else if (i < 512) { g = gk; bb = bk; mm = mk; vv_ = vk; o = i - 256; }
        else              { g = gv; bb = bv; mm = mv; vv_ = vv; o = i - 512; }
        float s = g[o] * rsqrtf(vv_[o] + 1e-5f);
        s_qkv[i] = s * post;
        t_qkv[i] = (bb[o] - mm[o] * s) * post;
        if (i < 384) {
            float sp = gp[i] * rsqrtf(vp[i] + 1e-5f);
            s_p[i] = sp;
            t_p[i] = bp[i] - mp[i] * sp;
        }
    }
    const int NQKV = 1024 * 384;
    if (i < NQKV) {
        int o = i / 384;
        float v;
        if (o < 256)      v = wq[i];
        else if (o < 512) v = wk[i - 256 * 384];
        else              v = wv[i - 512 * 384];
        wqkv[i] = f2bs(v);
    } else {
        int j = i - NQKV;
        if (j < 384 * 512) wpb[j] = f2bs(wp[j]);
    }
}

// ---------------- QKV GEMM: LDS-staged 128x128 tile, BK=64 (2 sub-phases/barrier) ----------------
__global__ __launch_bounds__(256, 2) void k_gemm_qkv(
    const short* __restrict__ wqkv, const short* __restrict__ xt,
    const float* __restrict__ s_qkv, const float* __restrict__ t_qkv,
    short* __restrict__ Qw, short* __restrict__ Kw, short* __restrict__ Vw) {
    __shared__ short AB[2][16384];  // A [128][64] + B [128][64] shorts per buffer
    const int t = threadIdx.x, lane = t & 63, w = t >> 6;
    const int g = lane >> 4, l15 = lane & 15;
    const int wr = w >> 1, wc = w & 1;
    const int jb = blockIdx.x, mb = blockIdx.y;

    const int ar = t >> 3, au = t & 7;
    const int aperm = 8 * (au ^ (ar & 7));
    const short* gA = wqkv + (size_t)(mb * 128 + ar) * 384 + aperm;
    const short* gB = xt + (size_t)((size_t)jb * 128 + ar) * 384 + aperm;

    f32x4 acc[4][4];
#pragma unroll
    for (int mi = 0; mi < 4; ++mi)
#pragma unroll
        for (int ni = 0; ni < 4; ++ni) acc[mi][ni] = f32x4{0.f, 0.f, 0.f, 0.f};

    auto stage = [&](int kt, int buf) {
        short* base = AB[buf];
#pragma unroll
        for (int jj = 0; jj < 4; ++jj) {
            gl_lds16(gA + (size_t)(32 * jj) * 384 + kt * 64, base + t * 8 + jj * 2048);
            gl_lds16(gB + (size_t)(32 * jj) * 384 + kt * 64, base + 8192 + t * 8 + jj * 2048);
        }
    };

    stage(0, 0);
    __syncthreads();

    for (int kt = 0; kt < 6; ++kt) {
        if (kt < 5) stage(kt + 1, (kt + 1) & 1);
        const short* base = AB[kt & 1];
#pragma unroll
        for (int ksub = 0; ksub < 2; ++ksub) {
            const int kc = 8 * ((4 * ksub + g) ^ (l15 & 7));
            s16x8 a[4], b[4];
#pragma unroll
            for (int mi = 0; mi < 4; ++mi)
                a[mi] = *(const s16x8*)(base + (64 * wr + 16 * mi + l15) * 64 + kc);
#pragma unroll
            for (int ni = 0; ni < 4; ++ni)
                b[ni] = *(const s16x8*)(base + 8192 + (64 * wc + 16 * ni + l15) * 64 + kc);
#pragma unroll
            for (int mi = 0; mi < 4; ++mi)
#pragma unroll
                for (int ni = 0; ni < 4; ++ni)
                    acc[mi][ni] = mfma16(a[mi], b[ni], acc[mi][ni]);
        }
        __syncthreads();
    }

    const int m_base = mb * 128 + 64 * wr;
    const int j_base = jb * 128 + 64 * wc;
#pragma unroll
    for (int mi = 0; mi < 4; ++mi) {
        const int o0 = m_base + 16 * mi;
#pragma unroll
        for (int ni = 0; ni < 4; ++ni) {
            const int j = j_base + 16 * ni + l15;
            const int bb = j >> 10, n = j & 1023;
            if (o0 < 512) {
                const int o = o0 + 4 * g;
                const int isK = o0 >= 256;
                const int o2 = o - (isK ? 256 : 0);
                const int h = o2 >> 5, d0 = o2 & 31;
                s16x4 ov;
#pragma unroll
                for (int r = 0; r < 4; ++r)
                    ov[r] = f2bs(acc[mi][ni][r] * s_qkv[o + r] + t_qkv[o + r]);
                short* dst = (isK ? Kw : Qw) + (((size_t)bb * 8 + h) * 1024 + n) * 32 + d0;
                *(s16x4*)dst = ov;
            } else {
#pragma unroll
                for (int r = 0; r < 4; ++r) {
                    const int o = o0 + 4 * g + r;
                    float val = acc[mi][ni][r] * s_qkv[o] + t_qkv[o];
                    const int o2 = o - 512;
                    const int h = o2 >> 6, e = o2 & 63;
                    Vw[(((size_t)bb * 8 + h) * 64 + e) * 1024 + n] = f2bs(val);
                }
            }
        }
    }
}

// ---------------- attention per (b,h): LDS-staged K/V, KVBLK=128, ones-MFMA l ----------------
// Permuted-K trick: S^T D-layout == PV B-layout, P stays in registers.
// l[n] computed by lacc = mfma(ones, pb, lacc): D[row][col] = sum_k P[k][col] -> every
// lane ends with the full softmax denominator of its column; no reduction needed.
__global__ __launch_bounds__(256, 2) void k_attn(const short* __restrict__ Qw,
                                                 const short* __restrict__ Kw,
                                                 const short* __restrict__ Vw,
                                                 short* __restrict__ Ow) {
    __shared__ short KV[2][12288];  // K 4096 + V 8192 shorts per buffer
    const int t = threadIdx.x, lane = t & 63, w = t >> 6;
    const int g = lane >> 4, l15 = lane & 15;
    const int low3 = blockIdx.x & 7;
    const int mid = blockIdx.x >> 3;
    const int rb = mid & 7;
    const int bh = ((mid >> 3) << 3) | low3;
    const int n_base = rb * 128 + w * 32;
    const short* Qb = Qw + (size_t)bh * (1024 * 32);
    const short* Kb = Kw + (size_t)bh * (1024 * 32);
    const short* Vb = Vw + (size_t)bh * (64 * 1024);

    s16x8 qf[2];
#pragma unroll
    for (int i = 0; i < 2; ++i)
        qf[i] = *(const s16x8*)(Qb + (size_t)(n_base + 16 * i + l15) * 32 + 8 * g);

    const s16x8 onesf = {0x3F80, 0x3F80, 0x3F80, 0x3F80, 0x3F80, 0x3F80, 0x3F80, 0x3F80};

    const int skr = t >> 2, sku = t & 3;
    const short* gK = Kb + (size_t)skr * 32 + 8 * (sku ^ (skr & 3));
    const int vr = t >> 4, vu = t & 15;
    const short* gV = Vb + (size_t)vr * 1024 + 8 * (vu ^ (vr & 7));

    f32x4 oacc[2][4], lacc[2];
#pragma unroll
    for (int niq = 0; niq < 2; ++niq) {
        lacc[niq] = f32x4{0.f, 0.f, 0.f, 0.f};
#pragma unroll
        for (int ei = 0; ei < 4; ++ei) oacc[niq][ei] = f32x4{0.f, 0.f, 0.f, 0.f};
    }

    const int krow = 8 * (l15 >> 2) + (l15 & 3);
    const int kcol = 8 * (g ^ (l15 & 3));

    auto stage = [&](int m0, int buf) {
        short* base = KV[buf];
        gl_lds16(gK + m0 * 32, base + t * 8);
        gl_lds16(gK + (m0 + 64) * 32, base + (t + 256) * 8);
#pragma unroll
        for (int jj = 0; jj < 4; ++jj)
            gl_lds16(gV + (size_t)(16 * jj) * 1024 + m0, base + 4096 + t * 8 + jj * 2048);
    };

    stage(0, 0);
    __syncthreads();

    for (int mt = 0; mt < 8; ++mt) {
        if (mt < 7) stage((mt + 1) * 128, (mt + 1) & 1);
        const short* base = KV[mt & 1];
#pragma unroll
        for (int msub = 0; msub < 2; ++msub) {
            const int mofs = 64 * msub;
            s16x8 kf[4];
            kf[0] = *(const s16x8*)(base + (krow + mofs + 0) * 32 + kcol);
            kf[1] = *(const s16x8*)(base + (krow + mofs + 4) * 32 + kcol);
            kf[2] = *(const s16x8*)(base + (krow + mofs + 32) * 32 + kcol);
            kf[3] = *(const s16x8*)(base + (krow + mofs + 36) * 32 + kcol);
            s16x8 vb[2][4];
#pragma unroll
            for (int ki = 0; ki < 2; ++ki)
#pragma unroll
                for (int ei = 0; ei < 4; ++ei) {
                    const int row = 16 * ei + l15;
                    vb[ki][ei] = *(const s16x8*)(base + 4096 + row * 128 +
                                                 8 * ((8 * msub + 4 * ki + g) ^ (row & 7)));
                }
            // S^T
            __builtin_amdgcn_s_setprio(1);
            f32x4 st[4][2];
#pragma unroll
            for (int mik = 0; mik < 4; ++mik)
#pragma unroll
                for (int niq = 0; niq < 2; ++niq)
                    st[mik][niq] = mfma16(kf[mik], qf[niq], f32x4{0.f, 0.f, 0.f, 0.f});
            __builtin_amdgcn_s_setprio(0);
            // P = exp2(S'); pack via __float2bfloat16 (pairs -> v_cvt_pk_bf16_f32)
            s16x4 pk[4][2];
#pragma unroll
            for (int mik = 0; mik < 4; ++mik)
#pragma unroll
                for (int niq = 0; niq < 2; ++niq) {
#pragma unroll
                    for (int r = 0; r < 4; ++r) {
                        float p = __builtin_amdgcn_exp2f(st[mik][niq][r]);
                        pk[mik][niq][r] =
                            __builtin_bit_cast(short, __float2bfloat16(p));
                    }
                }
            // PV + l: B-frag = concat(pk[2ki], pk[2ki+1]); lacc = mfma(ones, pb, lacc)
            __builtin_amdgcn_s_setprio(1);
#pragma unroll
            for (int ki = 0; ki < 2; ++ki)
#pragma unroll
                for (int niq = 0; niq < 2; ++niq) {
                    s16x8 pb = __builtin_shufflevector(pk[2 * ki][niq], pk[2 * ki + 1][niq],
                                                       0, 1, 2, 3, 4, 5, 6, 7);
                    lacc[niq] = mfma16(onesf, pb, lacc[niq]);
#pragma unroll
                    for (int ei = 0; ei < 4; ++ei)
                        oacc[niq][ei] = mfma16(vb[ki][ei], pb, oacc[niq][ei]);
                }
            __builtin_amdgcn_s_setprio(0);
        }
        __syncthreads();
    }

    // l is complete in every lane (row-broadcast by ones-MFMA)
    float li[2];
#pragma unroll
    for (int niq = 0; niq < 2; ++niq) li[niq] = __builtin_amdgcn_rcpf(lacc[niq][0]);

    const int b = bh >> 3, h = bh & 7;
#pragma unroll
    for (int niq = 0; niq < 2; ++niq) {
        const int n = n_base + 16 * niq + l15;
#pragma unroll
        for (int ei = 0; ei < 4; ++ei) {
            s16x4 ov;
#pragma unroll
            for (int r = 0; r < 4; ++r)
                ov[r] = f2bs(fmaxf(oacc[niq][ei][r] * li[niq], 0.f));
            *(s16x4*)(Ow + ((size_t)b * 1024 + n) * 512 + h * 64 + 16 * ei + 4 * g) = ov;
        }
    }
}

// ---------------- proj GEMM: LDS-staged 64x64 tile, BK=64 (2 sub-phases/barrier) ----------------
__global__ __launch_bounds__(256, 3) void k_proj(const short* __restrict__ wpb,
                                                 const short* __restrict__ Ow,
                                                 const float* __restrict__ s_p,
                                                 const float* __restrict__ t_p,
                                                 float* __restrict__ out) {
    __shared__ short AB[2][8192];
    const int t = threadIdx.x, lane = t & 63, w = t >> 6;
    const int g = lane >> 4, l15 = lane & 15;
    const int wr = w >> 1, wc = w & 1;
    const int jb = blockIdx.x, mb = blockIdx.y;

    const int ar = t >> 3, au = t & 7;
    const int aperm = 8 * (au ^ (ar & 7));
    const short* gA = wpb + (size_t)(mb * 64 + ar) * 512 + aperm;
    const short* gB = Ow + (size_t)((size_t)jb * 64 + ar) * 512 + aperm;

    f32x4 acc[2][2];
#pragma unroll
    for (int mi = 0; mi < 2; ++mi)
#pragma unroll
        for (int ni = 0; ni < 2; ++ni) acc[mi][ni] = f32x4{0.f, 0.f, 0.f, 0.f};

    auto stage = [&](int kt, int buf) {
        short* base = AB[buf];
#pragma unroll
        for (int jj = 0; jj < 2; ++jj) {
            gl_lds16(gA + (size_t)(32 * jj) * 512 + kt * 64, base + t * 8 + jj * 2048);
            gl_lds16(gB + (size_t)(32 * jj) * 512 + kt * 64, base + 4096 + t * 8 + jj * 2048);
        }
    };

    stage(0, 0);
    __syncthreads();

    for (int kt = 0; kt < 8; ++kt) {
        if (kt < 7) stage(kt + 1, (kt + 1) & 1);
        const short* base = AB[kt & 1];
#pragma unroll
        for (int ksub = 0; ksub < 2; ++ksub) {
            const int kc = 8 * ((4 * ksub + g) ^ (l15 & 7));
            s16x8 a[2], b[2];
#pragma unroll
            for (int mi = 0; mi < 2; ++mi)
                a[mi] = *(const s16x8*)(base + (32 * wr + 16 * mi + l15) * 64 + kc);
#pragma unroll
            for (int ni = 0; ni < 2; ++ni)
                b[ni] = *(const s16x8*)(base + 4096 + (32 * wc + 16 * ni + l15) * 64 + kc);
#pragma unroll
            for (int mi = 0; mi < 2; ++mi)
#pragma unroll
                for (int ni = 0; ni < 2; ++ni)
                    acc[mi][ni] = mfma16(a[mi], b[ni], acc[mi][ni]);
        }
        __syncthreads();
    }

    const int m_base = mb * 64 + 32 * wr;
    const int j_base = jb * 64 + 32 * wc;
#pragma unroll
    for (int mi = 0; mi < 2; ++mi) {
#pragma unroll
        for (int ni = 0; ni < 2; ++ni) {
            const int j = j_base + 16 * ni + l15;
            const int bb = j >> 10, n = j & 1023;
#pragma unroll
            for (int r = 0; r < 4; ++r) {
                const int c = m_base + 16 * mi + 4 * g + r;
                float v = acc[mi][ni][r] * s_p[c] + t_p[c];
                out[((size_t)bb * 384 + c) * 1024 + n] = v;
            }
        }
    }
}

extern "C" void kernel_launch(void* const* d_in, const int* in_sizes, int n_in,
                              void* d_out, int out_size, void* d_ws, size_t ws_size,
                              hipStream_t stream) {
    const float* x  = (const float*)d_in[0];
    const float* wq = (const float*)d_in[1];
    const float* gq = (const float*)d_in[2];
    const float* bq = (const float*)d_in[3];
    const float* mq = (const float*)d_in[4];
    const float* vq = (const float*)d_in[5];
    const float* wk = (const float*)d_in[6];
    const float* gk = (const float*)d_in[7];
    const float* bk = (const float*)d_in[8];
    const float* mk = (const float*)d_in[9];
    const float* vk = (const float*)d_in[10];
    const float* wv = (const float*)d_in[11];
    const float* gv = (const float*)d_in[12];
    const float* bv = (const float*)d_in[13];
    const float* mv = (const float*)d_in[14];
    const float* vv = (const float*)d_in[15];
    const float* wp = (const float*)d_in[16];
    const float* gp = (const float*)d_in[17];
    const float* bp = (const float*)d_in[18];
    const float* mp = (const float*)d_in[19];
    const float* vp = (const float*)d_in[20];
    float* out = (float*)d_out;

    char* ws = (char*)d_ws;
    size_t off = 0;
    auto alloc = [&](size_t bytes) {
        char* p = ws + off;
        off += (bytes + 255) & ~(size_t)255;
        return p;
    };
    short* xt    = (short*)alloc((size_t)8 * 1024 * 384 * 2);
    short* wqkv  = (short*)alloc((size_t)1024 * 384 * 2);
    short* wpb   = (short*)alloc((size_t)384 * 512 * 2);
    float* s_qkv = (float*)alloc(1024 * 4);
    float* t_qkv = (float*)alloc(1024 * 4);
    float* s_p   = (float*)alloc(384 * 4);
    float* t_p   = (float*)alloc(384 * 4);
    short* Qw    = (short*)alloc((size_t)8 * 8 * 1024 * 32 * 2);
    short* Kw    = (short*)alloc((size_t)8 * 8 * 1024 * 32 * 2);
    short* Vw    = (short*)alloc((size_t)8 * 8 * 64 * 1024 * 2);
    short* Ow    = (short*)alloc((size_t)8 * 1024 * 512 * 2);
    (void)ws_size; (void)in_sizes; (void)n_in; (void)out_size;

    k_prep<<<dim3(3072 + 2304), 256, 0, stream>>>(
        x, xt, wq, wk, wv, wp, wqkv, wpb,
        gq, bq, mq, vq, gk, bk, mk, vk, gv, bv, mv, vv, gp, bp, mp, vp,
        s_qkv, t_qkv, s_p, t_p);
    k_gemm_qkv<<<dim3(64, 8), 256, 0, stream>>>(wqkv, xt, s_qkv, t_qkv, Qw, Kw, Vw);
    k_attn<<<dim3(512), 256, 0, stream>>>(Qw, Kw, Vw, Ow);
    k_proj<<<dim3(128, 6), 256, 0, stream>>>(wpb, Ow, s_p, t_p, out);
}